// Round 4
// baseline (741.133 us; speedup 1.0000x reference)
//
#include <hip/hip_runtime.h>
#include <math.h>

#define D 64
#define NUM_USERS 100000
#define NUM_ITEMS 50000
#define N_NODES 150000   // NUM_USERS + NUM_ITEMS
#define NNZ 2400000
#define BATCH 8192
#define NEG_SLOPE 0.1f
#define EPS_NRM 1e-12f

#define NB ((N_NODES + 255) / 256)   // 586 scan blocks (<=1024)

typedef unsigned short ushort_t;

__device__ __forceinline__ float wave_sum64(float v) {
    #pragma unroll
    for (int off = 32; off > 0; off >>= 1)
        v += __shfl_xor(v, off, 64);
    return v;
}

__device__ __forceinline__ ushort_t f2bf(float f) {
    unsigned x = __float_as_uint(f);
    unsigned r = (x + 0x7FFFu + ((x >> 16) & 1u)) >> 16;   // RNE
    return (ushort_t)r;
}

// ---------- CSR build: linked list + compaction (no random scatter) ----------
// head[r]=-1 initially; nxt[e] = previous head. cnt histogram for rowptr.
__global__ void build_list_kernel(const int* __restrict__ rows,
                                  int* __restrict__ head,
                                  int* __restrict__ nxt,
                                  int* __restrict__ cnt) {
    int e = blockIdx.x * 256 + threadIdx.x;
    if (e < NNZ) {
        int r = rows[e];
        atomicAdd(&cnt[r], 1);
        int old = atomicExch(&head[r], e);
        nxt[e] = old;          // coalesced sequential write
    }
}

__global__ void scan1_kernel(const int* __restrict__ in, int* __restrict__ out,
                             int* __restrict__ bsums) {
    int tid = threadIdx.x, gid = blockIdx.x * 256 + tid;
    int v = (gid < N_NODES) ? in[gid] : 0;
    int lane = tid & 63, w = tid >> 6;
    int s = v;
    #pragma unroll
    for (int off = 1; off < 64; off <<= 1) {
        int t = __shfl_up(s, off, 64);
        if (lane >= off) s += t;
    }
    __shared__ int wsum[4];
    if (lane == 63) wsum[w] = s;
    __syncthreads();
    if (tid == 0) {
        int a = 0;
        #pragma unroll
        for (int i = 0; i < 4; i++) { int t = wsum[i]; wsum[i] = a; a += t; }
    }
    __syncthreads();
    int incl = s + wsum[w];
    if (gid < N_NODES) out[gid] = incl - v;     // exclusive
    if (tid == 255) bsums[blockIdx.x] = incl;   // block total
}

__global__ void scan2_kernel(int* __restrict__ bsums, int n) {
    int tid = threadIdx.x;
    int v = (tid < n) ? bsums[tid] : 0;
    int lane = tid & 63, w = tid >> 6;
    int s = v;
    #pragma unroll
    for (int off = 1; off < 64; off <<= 1) {
        int t = __shfl_up(s, off, 64);
        if (lane >= off) s += t;
    }
    __shared__ int wsum[16];
    if (lane == 63) wsum[w] = s;
    __syncthreads();
    if (tid == 0) {
        int a = 0;
        #pragma unroll
        for (int i = 0; i < 16; i++) { int t = wsum[i]; wsum[i] = a; a += t; }
    }
    __syncthreads();
    int incl = s + wsum[w];
    if (tid < n) bsums[tid] = incl - v;
}

__global__ void scan3_kernel(int* __restrict__ rowptr, const int* __restrict__ bsums) {
    int gid = blockIdx.x * 256 + threadIdx.x;
    if (gid < N_NODES)
        rowptr[gid] += bsums[blockIdx.x];
    if (gid == 0) rowptr[N_NODES] = NNZ;
}

// one THREAD per row: walk the linked list, write the row's edges contiguously.
__global__ void compact_kernel(const int* __restrict__ head,
                               const int* __restrict__ nxt,
                               const int* __restrict__ cols,
                               const float* __restrict__ vals,
                               const int* __restrict__ rowptr,
                               int2* __restrict__ es) {
    int r = blockIdx.x * 256 + threadIdx.x;
    if (r >= N_NODES) return;
    int slot = rowptr[r];
    int e = head[r];
    while (e >= 0) {
        es[slot++] = make_int2(cols[e], __float_as_int(vals[e]));
        e = nxt[e];
    }
}

// ---------- GCN ----------
__global__ void init_kernel(const float* __restrict__ upref,
                            const float* __restrict__ ipref,
                            float* __restrict__ acc,
                            ushort_t* __restrict__ p) {
    int row  = blockIdx.x * 4 + (threadIdx.x >> 6);
    int lane = threadIdx.x & 63;
    if (row >= N_NODES) return;
    float x = (row < NUM_USERS) ? upref[(size_t)row * D + lane]
                                : ipref[(size_t)(row - NUM_USERS) * D + lane];
    x = (x >= 0.f) ? x : NEG_SLOPE * x;
    float norm = sqrtf(wave_sum64(x * x));
    float y = x / fmaxf(norm, EPS_NRM);
    size_t idx = (size_t)row * D + lane;
    acc[idx] = y;
    p[idx]   = f2bf(y);
}

// one wave per row; 8 edges in flight (sub = lane>>3), 8 features/lane (fl = lane&7)
__global__ void gather_kernel(const int* __restrict__ rowptr,
                              const int2* __restrict__ es,
                              const ushort_t* __restrict__ p,
                              ushort_t* __restrict__ pn,
                              float* __restrict__ acc) {
    int row  = blockIdx.x * 4 + (threadIdx.x >> 6);
    int lane = threadIdx.x & 63;
    if (row >= N_NODES) return;
    int sub = lane >> 3;
    int fl  = lane & 7;
    int beg = rowptr[row], end = rowptr[row + 1];

    float a[8];
    #pragma unroll
    for (int k = 0; k < 8; k++) a[k] = 0.f;

    for (int e = beg + sub; e < end; e += 8) {
        int2 cv = es[e];
        float v = __int_as_float(cv.y);
        const uint4 q = *(const uint4*)(p + (size_t)cv.x * D + fl * 8);
        a[0] = fmaf(v, __uint_as_float(q.x << 16),         a[0]);
        a[1] = fmaf(v, __uint_as_float(q.x & 0xFFFF0000u), a[1]);
        a[2] = fmaf(v, __uint_as_float(q.y << 16),         a[2]);
        a[3] = fmaf(v, __uint_as_float(q.y & 0xFFFF0000u), a[3]);
        a[4] = fmaf(v, __uint_as_float(q.z << 16),         a[4]);
        a[5] = fmaf(v, __uint_as_float(q.z & 0xFFFF0000u), a[5]);
        a[6] = fmaf(v, __uint_as_float(q.w << 16),         a[6]);
        a[7] = fmaf(v, __uint_as_float(q.w & 0xFFFF0000u), a[7]);
    }
    // reduce across the 8 sub-groups (lane bits 3,4,5)
    #pragma unroll
    for (int k = 0; k < 8; k++) {
        a[k] += __shfl_xor(a[k], 8, 64);
        a[k] += __shfl_xor(a[k], 16, 64);
        a[k] += __shfl_xor(a[k], 32, 64);
    }

    float ss = 0.f;
    #pragma unroll
    for (int k = 0; k < 8; k++) {
        a[k] = (a[k] >= 0.f) ? a[k] : NEG_SLOPE * a[k];
        ss = fmaf(a[k], a[k], ss);
    }
    // norm reduce across fl (lane bits 0,1,2)
    ss += __shfl_xor(ss, 1, 64);
    ss += __shfl_xor(ss, 2, 64);
    ss += __shfl_xor(ss, 4, 64);
    float inv = 1.f / fmaxf(sqrtf(ss), EPS_NRM);
    #pragma unroll
    for (int k = 0; k < 8; k++) a[k] *= inv;

    if (sub == 0) {
        uint4 o;
        o.x = (unsigned)f2bf(a[0]) | ((unsigned)f2bf(a[1]) << 16);
        o.y = (unsigned)f2bf(a[2]) | ((unsigned)f2bf(a[3]) << 16);
        o.z = (unsigned)f2bf(a[4]) | ((unsigned)f2bf(a[5]) << 16);
        o.w = (unsigned)f2bf(a[6]) | ((unsigned)f2bf(a[7]) << 16);
        *(uint4*)(pn + (size_t)row * D + fl * 8) = o;
    } else if (sub == 1) {
        float4* ap = (float4*)(acc + (size_t)row * D + fl * 8);
        float4 v0 = ap[0], v1 = ap[1];
        v0.x += a[0]; v0.y += a[1]; v0.z += a[2]; v0.w += a[3];
        v1.x += a[4]; v1.y += a[5]; v1.z += a[6]; v1.w += a[7];
        ap[0] = v0; ap[1] = v1;
    }
}

__global__ void score_kernel(const int* __restrict__ users,
                             const int* __restrict__ it0,
                             const int* __restrict__ it1,
                             const int* __restrict__ it2,
                             const float* __restrict__ acc,
                             float* __restrict__ out) {
    int task = blockIdx.x * 4 + (threadIdx.x >> 6);
    int lane = threadIdx.x & 63;
    if (task >= 3 * BATCH) return;
    int which = task >> 13;
    int b     = task & (BATCH - 1);
    int u  = users[b];
    int it = (which == 0) ? it0[b] : (which == 1) ? it1[b] : it2[b];
    float uv = acc[(size_t)u * D + lane] * 0.25f;
    float iv = acc[(size_t)(NUM_USERS + it) * D + lane] * 0.25f;
    float s  = wave_sum64(uv * iv);
    if (lane == 0)
        out[which * BATCH + b] = 1.f / (1.f + expf(-s));
}

extern "C" void kernel_launch(void* const* d_in, const int* in_sizes, int n_in,
                              void* d_out, int out_size, void* d_ws, size_t ws_size,
                              hipStream_t stream) {
    const int*   users  = (const int*)  d_in[0];
    const int*   adj    = (const int*)  d_in[1];
    const int*   weak   = (const int*)  d_in[2];
    const int*   strong = (const int*)  d_in[3];
    const int*   erows  = (const int*)  d_in[4];
    const int*   ecols  = (const int*)  d_in[5];
    const float* evals  = (const float*)d_in[6];
    const float* upref  = (const float*)d_in[7];
    const float* ipref  = (const float*)d_in[8];
    float* out = (float*)d_out;

    const size_t rowElems = (size_t)N_NODES * D;   // 9.6M

    char* base = (char*)d_ws;
    size_t off = 0;
    auto alloc = [&](size_t bytes) {
        char* p = base + off;
        off = (off + bytes + 255) & ~(size_t)255;
        return (void*)p;
    };
    float*    acc    = (float*)   alloc(rowElems * sizeof(float));    // 38.4 MB
    ushort_t* pA     = (ushort_t*)alloc(rowElems * sizeof(ushort_t)); // 19.2 MB
    ushort_t* pB     = (ushort_t*)alloc(rowElems * sizeof(ushort_t)); // 19.2 MB
    int2*     es     = (int2*)    alloc((size_t)NNZ * sizeof(int2));  // 19.2 MB
    int*      nxt    = (int*)     alloc((size_t)NNZ * sizeof(int));   // 9.6 MB
    int*      head   = (int*)     alloc(N_NODES * sizeof(int));
    int*      rowptr = (int*)     alloc((N_NODES + 1) * sizeof(int));
    int*      rcnt   = (int*)     alloc(N_NODES * sizeof(int));
    int*      bsums  = (int*)     alloc(1024 * sizeof(int));

    // ---- build CSR via linked lists (once per launch) ----
    hipMemsetAsync(rcnt, 0, N_NODES * sizeof(int), stream);
    hipMemsetAsync(head, 0xFF, N_NODES * sizeof(int), stream);   // head = -1
    build_list_kernel<<<(NNZ + 255) / 256, 256, 0, stream>>>(erows, head, nxt, rcnt);
    scan1_kernel<<<NB, 256, 0, stream>>>(rcnt, rowptr, bsums);
    scan2_kernel<<<1, 1024, 0, stream>>>(bsums, NB);
    scan3_kernel<<<NB, 256, 0, stream>>>(rowptr, bsums);
    compact_kernel<<<NB, 256, 0, stream>>>(head, nxt, ecols, evals, rowptr, es);

    // ---- GCN layers ----
    init_kernel<<<(N_NODES + 3) / 4, 256, 0, stream>>>(upref, ipref, acc, pA);

    ushort_t* pc = pA;
    ushort_t* pn = pB;
    for (int l = 0; l < 3; ++l) {
        gather_kernel<<<(N_NODES + 3) / 4, 256, 0, stream>>>(rowptr, es, pc, pn, acc);
        ushort_t* t = pc; pc = pn; pn = t;
    }

    score_kernel<<<(3 * BATCH + 3) / 4, 256, 0, stream>>>(users, adj, weak, strong, acc, out);
}

// Round 5
// 451.428 us; speedup vs baseline: 1.6418x; 1.6418x over previous
//
#include <hip/hip_runtime.h>
#include <math.h>

#define D 64
#define NUM_USERS 100000
#define NUM_ITEMS 50000
#define N_NODES 150000   // NUM_USERS + NUM_ITEMS
#define NNZ 2400000
#define BATCH 8192
#define NEG_SLOPE 0.1f
#define EPS_NRM 1e-12f

// bucket sort geometry: bucket = row >> 9 (512 rows/bucket)
#define NBUCKET 293                 // ceil(150000/512)
#define NCHUNK  512
#define CH      4688                // ceil(NNZ/NCHUNK)
#define NH      (NBUCKET * NCHUNK)  // 150016 (= 586*256 exactly)
#define NBH     (NH / 256)          // 586 scan blocks

typedef unsigned short ushort_t;

__device__ __forceinline__ float wave_sum64(float v) {
    #pragma unroll
    for (int off = 32; off > 0; off >>= 1)
        v += __shfl_xor(v, off, 64);
    return v;
}

__device__ __forceinline__ ushort_t f2bf(float f) {
    unsigned x = __float_as_uint(f);
    unsigned r = (x + 0x7FFFu + ((x >> 16) & 1u)) >> 16;   // RNE
    return (ushort_t)r;
}

// ---------- CSR build: 2-level bucket sort, LDS atomics only ----------

// per-chunk histogram over buckets -> ht[bucket][chunk] (bucket-major for the scan)
__global__ void bucket_hist(const int* __restrict__ rows, int* __restrict__ ht) {
    __shared__ int hist[NBUCKET];
    int c = blockIdx.x, tid = threadIdx.x;
    for (int b = tid; b < NBUCKET; b += 256) hist[b] = 0;
    __syncthreads();
    int base = c * CH;
    for (int i = tid; i < CH; i += 256) {
        int e = base + i;
        if (e < NNZ) atomicAdd(&hist[rows[e] >> 9], 1);
    }
    __syncthreads();
    for (int b = tid; b < NBUCKET; b += 256) ht[b * NCHUNK + c] = hist[b];
}

// generic 256/block exclusive scan over n elems
__global__ void scan1_kernel(const int* __restrict__ in, int* __restrict__ out,
                             int* __restrict__ bsums, int n) {
    int tid = threadIdx.x, gid = blockIdx.x * 256 + tid;
    int v = (gid < n) ? in[gid] : 0;
    int lane = tid & 63, w = tid >> 6;
    int s = v;
    #pragma unroll
    for (int off = 1; off < 64; off <<= 1) {
        int t = __shfl_up(s, off, 64);
        if (lane >= off) s += t;
    }
    __shared__ int wsum[4];
    if (lane == 63) wsum[w] = s;
    __syncthreads();
    if (tid == 0) {
        int a = 0;
        #pragma unroll
        for (int i = 0; i < 4; i++) { int t = wsum[i]; wsum[i] = a; a += t; }
    }
    __syncthreads();
    int incl = s + wsum[w];
    if (gid < n) out[gid] = incl - v;           // exclusive
    if (tid == 255) bsums[blockIdx.x] = incl;   // block total
}

__global__ void scan2_kernel(int* __restrict__ bsums, int n) {
    int tid = threadIdx.x;
    int v = (tid < n) ? bsums[tid] : 0;
    int lane = tid & 63, w = tid >> 6;
    int s = v;
    #pragma unroll
    for (int off = 1; off < 64; off <<= 1) {
        int t = __shfl_up(s, off, 64);
        if (lane >= off) s += t;
    }
    __shared__ int wsum[16];
    if (lane == 63) wsum[w] = s;
    __syncthreads();
    if (tid == 0) {
        int a = 0;
        #pragma unroll
        for (int i = 0; i < 16; i++) { int t = wsum[i]; wsum[i] = a; a += t; }
    }
    __syncthreads();
    int incl = s + wsum[w];
    if (tid < n) bsums[tid] = incl - v;
}

__global__ void scan3_kernel(int* __restrict__ out, const int* __restrict__ bsums, int n) {
    int gid = blockIdx.x * 256 + threadIdx.x;
    if (gid < n) out[gid] += bsums[blockIdx.x];
}

// chunk re-reads its edges, LDS cursors (seeded from scanned offsets), writes
// (col | rlow<<18, val) into bucketed es_tmp — per-(bucket,chunk) runs are contiguous
__global__ void bucket_scatter(const int* __restrict__ rows, const int* __restrict__ cols,
                               const float* __restrict__ vals, const int* __restrict__ hoff,
                               int2* __restrict__ est) {
    __shared__ int cur[NBUCKET];
    int c = blockIdx.x, tid = threadIdx.x;
    for (int b = tid; b < NBUCKET; b += 256) cur[b] = hoff[b * NCHUNK + c];
    __syncthreads();
    int base = c * CH;
    for (int i = tid; i < CH; i += 256) {
        int e = base + i;
        if (e < NNZ) {
            int r = rows[e];
            int pos = atomicAdd(&cur[r >> 9], 1);          // LDS atomic
            est[pos] = make_int2(cols[e] | ((r & 511) << 18), __float_as_int(vals[e]));
        }
    }
}

// one block per bucket: LDS histogram over the 512 local rows, block scan,
// LDS-cursor scatter into the dense per-bucket region; emits rowptr directly.
__global__ void __launch_bounds__(512) bucket_sort(const int2* __restrict__ est,
                                                   const int* __restrict__ hoff,
                                                   int2* __restrict__ es,
                                                   int* __restrict__ rowptr) {
    __shared__ int hist[512];
    __shared__ int wsum[8];
    int b = blockIdx.x, tid = threadIdx.x;
    int beg = hoff[b * NCHUNK];
    int end = (b == NBUCKET - 1) ? NNZ : hoff[(b + 1) * NCHUNK];
    hist[tid] = 0;
    __syncthreads();
    for (int i = beg + tid; i < end; i += 512)
        atomicAdd(&hist[est[i].x >> 18], 1);
    __syncthreads();
    // block exclusive scan of hist[512]
    int v = hist[tid];
    int lane = tid & 63, w = tid >> 6;
    int s = v;
    #pragma unroll
    for (int off = 1; off < 64; off <<= 1) {
        int t = __shfl_up(s, off, 64);
        if (lane >= off) s += t;
    }
    if (lane == 63) wsum[w] = s;
    __syncthreads();
    if (tid == 0) {
        int a = 0;
        #pragma unroll
        for (int i = 0; i < 8; i++) { int t = wsum[i]; wsum[i] = a; a += t; }
    }
    __syncthreads();
    int excl = s - v + wsum[w];
    // rowptr[base + tid] = beg + excl  (covers rowptr[N_NODES] via bucket 292, tid 496)
    int rbase = b << 9;
    if (rbase + tid <= N_NODES) rowptr[rbase + tid] = beg + excl;
    __syncthreads();
    hist[tid] = excl;            // reuse as cursor (beg-relative)
    __syncthreads();
    for (int i = beg + tid; i < end; i += 512) {
        int2 kv = est[i];
        int r9  = kv.x >> 18;
        int pos = beg + atomicAdd(&hist[r9], 1);           // LDS atomic
        es[pos] = make_int2(kv.x & 0x3FFFF, kv.y);
    }
}

// ---------- GCN ----------
__global__ void init_kernel(const float* __restrict__ upref,
                            const float* __restrict__ ipref,
                            float* __restrict__ acc,
                            ushort_t* __restrict__ p) {
    int row  = blockIdx.x * 4 + (threadIdx.x >> 6);
    int lane = threadIdx.x & 63;
    if (row >= N_NODES) return;
    float x = (row < NUM_USERS) ? upref[(size_t)row * D + lane]
                                : ipref[(size_t)(row - NUM_USERS) * D + lane];
    x = (x >= 0.f) ? x : NEG_SLOPE * x;
    float norm = sqrtf(wave_sum64(x * x));
    float y = x / fmaxf(norm, EPS_NRM);
    size_t idx = (size_t)row * D + lane;
    acc[idx] = y;
    p[idx]   = f2bf(y);
}

// one wave per row; 8 edges in flight (sub = lane>>3), 8 features/lane (fl = lane&7)
__global__ void gather_kernel(const int* __restrict__ rowptr,
                              const int2* __restrict__ es,
                              const ushort_t* __restrict__ p,
                              ushort_t* __restrict__ pn,
                              float* __restrict__ acc) {
    int row  = blockIdx.x * 4 + (threadIdx.x >> 6);
    int lane = threadIdx.x & 63;
    if (row >= N_NODES) return;
    int sub = lane >> 3;
    int fl  = lane & 7;
    int beg = rowptr[row], end = rowptr[row + 1];

    float a[8];
    #pragma unroll
    for (int k = 0; k < 8; k++) a[k] = 0.f;

    for (int e = beg + sub; e < end; e += 8) {
        int2 cv = es[e];
        float v = __int_as_float(cv.y);
        const uint4 q = *(const uint4*)(p + (size_t)cv.x * D + fl * 8);
        a[0] = fmaf(v, __uint_as_float(q.x << 16),         a[0]);
        a[1] = fmaf(v, __uint_as_float(q.x & 0xFFFF0000u), a[1]);
        a[2] = fmaf(v, __uint_as_float(q.y << 16),         a[2]);
        a[3] = fmaf(v, __uint_as_float(q.y & 0xFFFF0000u), a[3]);
        a[4] = fmaf(v, __uint_as_float(q.z << 16),         a[4]);
        a[5] = fmaf(v, __uint_as_float(q.z & 0xFFFF0000u), a[5]);
        a[6] = fmaf(v, __uint_as_float(q.w << 16),         a[6]);
        a[7] = fmaf(v, __uint_as_float(q.w & 0xFFFF0000u), a[7]);
    }
    #pragma unroll
    for (int k = 0; k < 8; k++) {
        a[k] += __shfl_xor(a[k], 8, 64);
        a[k] += __shfl_xor(a[k], 16, 64);
        a[k] += __shfl_xor(a[k], 32, 64);
    }

    float ss = 0.f;
    #pragma unroll
    for (int k = 0; k < 8; k++) {
        a[k] = (a[k] >= 0.f) ? a[k] : NEG_SLOPE * a[k];
        ss = fmaf(a[k], a[k], ss);
    }
    ss += __shfl_xor(ss, 1, 64);
    ss += __shfl_xor(ss, 2, 64);
    ss += __shfl_xor(ss, 4, 64);
    float inv = 1.f / fmaxf(sqrtf(ss), EPS_NRM);
    #pragma unroll
    for (int k = 0; k < 8; k++) a[k] *= inv;

    if (sub == 0) {
        uint4 o;
        o.x = (unsigned)f2bf(a[0]) | ((unsigned)f2bf(a[1]) << 16);
        o.y = (unsigned)f2bf(a[2]) | ((unsigned)f2bf(a[3]) << 16);
        o.z = (unsigned)f2bf(a[4]) | ((unsigned)f2bf(a[5]) << 16);
        o.w = (unsigned)f2bf(a[6]) | ((unsigned)f2bf(a[7]) << 16);
        *(uint4*)(pn + (size_t)row * D + fl * 8) = o;
    } else if (sub == 1) {
        float4* ap = (float4*)(acc + (size_t)row * D + fl * 8);
        float4 v0 = ap[0], v1 = ap[1];
        v0.x += a[0]; v0.y += a[1]; v0.z += a[2]; v0.w += a[3];
        v1.x += a[4]; v1.y += a[5]; v1.z += a[6]; v1.w += a[7];
        ap[0] = v0; ap[1] = v1;
    }
}

__global__ void score_kernel(const int* __restrict__ users,
                             const int* __restrict__ it0,
                             const int* __restrict__ it1,
                             const int* __restrict__ it2,
                             const float* __restrict__ acc,
                             float* __restrict__ out) {
    int task = blockIdx.x * 4 + (threadIdx.x >> 6);
    int lane = threadIdx.x & 63;
    if (task >= 3 * BATCH) return;
    int which = task >> 13;
    int b     = task & (BATCH - 1);
    int u  = users[b];
    int it = (which == 0) ? it0[b] : (which == 1) ? it1[b] : it2[b];
    float uv = acc[(size_t)u * D + lane] * 0.25f;
    float iv = acc[(size_t)(NUM_USERS + it) * D + lane] * 0.25f;
    float s  = wave_sum64(uv * iv);
    if (lane == 0)
        out[which * BATCH + b] = 1.f / (1.f + expf(-s));
}

extern "C" void kernel_launch(void* const* d_in, const int* in_sizes, int n_in,
                              void* d_out, int out_size, void* d_ws, size_t ws_size,
                              hipStream_t stream) {
    const int*   users  = (const int*)  d_in[0];
    const int*   adj    = (const int*)  d_in[1];
    const int*   weak   = (const int*)  d_in[2];
    const int*   strong = (const int*)  d_in[3];
    const int*   erows  = (const int*)  d_in[4];
    const int*   ecols  = (const int*)  d_in[5];
    const float* evals  = (const float*)d_in[6];
    const float* upref  = (const float*)d_in[7];
    const float* ipref  = (const float*)d_in[8];
    float* out = (float*)d_out;

    const size_t rowElems = (size_t)N_NODES * D;   // 9.6M

    char* base = (char*)d_ws;
    size_t off = 0;
    auto alloc = [&](size_t bytes) {
        char* p = base + off;
        off = (off + bytes + 255) & ~(size_t)255;
        return (void*)p;
    };
    float*    acc    = (float*)   alloc(rowElems * sizeof(float));    // 38.4 MB
    ushort_t* pA     = (ushort_t*)alloc(rowElems * sizeof(ushort_t)); // 19.2 MB
    ushort_t* pB     = (ushort_t*)alloc(rowElems * sizeof(ushort_t)); // 19.2 MB
    int2*     es     = (int2*)    alloc((size_t)NNZ * sizeof(int2));  // 19.2 MB
    int*      ht     = (int*)     alloc((size_t)NH * sizeof(int));    // 0.6 MB
    int*      hoff   = (int*)     alloc((size_t)NH * sizeof(int));    // 0.6 MB
    int*      rowptr = (int*)     alloc((N_NODES + 1) * sizeof(int));
    int*      bsums  = (int*)     alloc(1024 * sizeof(int));
    // es_tmp aliases acc: only live until bucket_sort finishes; init_kernel
    // (which writes acc) is stream-ordered after it.
    int2*     est    = (int2*)acc;                                    // 19.2 MB alias

    // ---- CSR build: bucket sort, zero global atomics ----
    bucket_hist   <<<NCHUNK, 256, 0, stream>>>(erows, ht);
    scan1_kernel  <<<NBH, 256, 0, stream>>>(ht, hoff, bsums, NH);
    scan2_kernel  <<<1, 1024, 0, stream>>>(bsums, NBH);
    scan3_kernel  <<<NBH, 256, 0, stream>>>(hoff, bsums, NH);
    bucket_scatter<<<NCHUNK, 256, 0, stream>>>(erows, ecols, evals, hoff, est);
    bucket_sort   <<<NBUCKET, 512, 0, stream>>>(est, hoff, es, rowptr);

    // ---- GCN layers ----
    init_kernel<<<(N_NODES + 3) / 4, 256, 0, stream>>>(upref, ipref, acc, pA);

    ushort_t* pc = pA;
    ushort_t* pn = pB;
    for (int l = 0; l < 3; ++l) {
        gather_kernel<<<(N_NODES + 3) / 4, 256, 0, stream>>>(rowptr, es, pc, pn, acc);
        ushort_t* t = pc; pc = pn; pn = t;
    }

    score_kernel<<<(3 * BATCH + 3) / 4, 256, 0, stream>>>(users, adj, weak, strong, acc, out);
}

// Round 6
// 424.270 us; speedup vs baseline: 1.7468x; 1.0640x over previous
//
#include <hip/hip_runtime.h>
#include <math.h>

#define D 64
#define NUM_USERS 100000
#define NUM_ITEMS 50000
#define N_NODES 150000   // NUM_USERS + NUM_ITEMS
#define NNZ 2400000
#define BATCH 8192
#define NEG_SLOPE 0.1f
#define EPS_NRM 1e-12f

// bucket sort geometry: bucket = row >> 9 (512 rows/bucket)
#define NBUCKET 293                 // ceil(150000/512)
#define NCHUNK  512
#define CH      4688                // ceil(NNZ/NCHUNK)
#define NH      (NBUCKET * NCHUNK)  // 150016 (= 586*256 exactly)
#define NBH     (NH / 256)          // 586 scan blocks

typedef unsigned short ushort_t;

__device__ __forceinline__ float wave_sum64(float v) {
    #pragma unroll
    for (int off = 32; off > 0; off >>= 1)
        v += __shfl_xor(v, off, 64);
    return v;
}

__device__ __forceinline__ float bf2f(ushort_t u) {
    return __uint_as_float(((unsigned)u) << 16);
}
__device__ __forceinline__ ushort_t f2bf(float f) {
    unsigned x = __float_as_uint(f);
    unsigned r = (x + 0x7FFFu + ((x >> 16) & 1u)) >> 16;   // RNE
    return (ushort_t)r;
}

// ---------- CSR build: 2-level bucket sort, LDS atomics only ----------

__global__ void bucket_hist(const int* __restrict__ rows, int* __restrict__ ht) {
    __shared__ int hist[NBUCKET];
    int c = blockIdx.x, tid = threadIdx.x;
    for (int b = tid; b < NBUCKET; b += 256) hist[b] = 0;
    __syncthreads();
    int base = c * CH;
    for (int i = tid; i < CH; i += 256) {
        int e = base + i;
        if (e < NNZ) atomicAdd(&hist[rows[e] >> 9], 1);
    }
    __syncthreads();
    for (int b = tid; b < NBUCKET; b += 256) ht[b * NCHUNK + c] = hist[b];
}

__global__ void scan1_kernel(const int* __restrict__ in, int* __restrict__ out,
                             int* __restrict__ bsums, int n) {
    int tid = threadIdx.x, gid = blockIdx.x * 256 + tid;
    int v = (gid < n) ? in[gid] : 0;
    int lane = tid & 63, w = tid >> 6;
    int s = v;
    #pragma unroll
    for (int off = 1; off < 64; off <<= 1) {
        int t = __shfl_up(s, off, 64);
        if (lane >= off) s += t;
    }
    __shared__ int wsum[4];
    if (lane == 63) wsum[w] = s;
    __syncthreads();
    if (tid == 0) {
        int a = 0;
        #pragma unroll
        for (int i = 0; i < 4; i++) { int t = wsum[i]; wsum[i] = a; a += t; }
    }
    __syncthreads();
    int incl = s + wsum[w];
    if (gid < n) out[gid] = incl - v;           // exclusive
    if (tid == 255) bsums[blockIdx.x] = incl;   // block total
}

__global__ void scan2_kernel(int* __restrict__ bsums, int n) {
    int tid = threadIdx.x;
    int v = (tid < n) ? bsums[tid] : 0;
    int lane = tid & 63, w = tid >> 6;
    int s = v;
    #pragma unroll
    for (int off = 1; off < 64; off <<= 1) {
        int t = __shfl_up(s, off, 64);
        if (lane >= off) s += t;
    }
    __shared__ int wsum[16];
    if (lane == 63) wsum[w] = s;
    __syncthreads();
    if (tid == 0) {
        int a = 0;
        #pragma unroll
        for (int i = 0; i < 16; i++) { int t = wsum[i]; wsum[i] = a; a += t; }
    }
    __syncthreads();
    int incl = s + wsum[w];
    if (tid < n) bsums[tid] = incl - v;
}

__global__ void scan3_kernel(int* __restrict__ out, const int* __restrict__ bsums, int n) {
    int gid = blockIdx.x * 256 + threadIdx.x;
    if (gid < n) out[gid] += bsums[blockIdx.x];
}

__global__ void bucket_scatter(const int* __restrict__ rows, const int* __restrict__ cols,
                               const float* __restrict__ vals, const int* __restrict__ hoff,
                               int2* __restrict__ est) {
    __shared__ int cur[NBUCKET];
    int c = blockIdx.x, tid = threadIdx.x;
    for (int b = tid; b < NBUCKET; b += 256) cur[b] = hoff[b * NCHUNK + c];
    __syncthreads();
    int base = c * CH;
    for (int i = tid; i < CH; i += 256) {
        int e = base + i;
        if (e < NNZ) {
            int r = rows[e];
            int pos = atomicAdd(&cur[r >> 9], 1);          // LDS atomic
            est[pos] = make_int2(cols[e] | ((r & 511) << 18), __float_as_int(vals[e]));
        }
    }
}

__global__ void __launch_bounds__(512) bucket_sort(const int2* __restrict__ est,
                                                   const int* __restrict__ hoff,
                                                   int2* __restrict__ es,
                                                   int* __restrict__ rowptr) {
    __shared__ int hist[512];
    __shared__ int wsum[8];
    int b = blockIdx.x, tid = threadIdx.x;
    int beg = hoff[b * NCHUNK];
    int end = (b == NBUCKET - 1) ? NNZ : hoff[(b + 1) * NCHUNK];
    hist[tid] = 0;
    __syncthreads();
    for (int i = beg + tid; i < end; i += 512)
        atomicAdd(&hist[est[i].x >> 18], 1);
    __syncthreads();
    int v = hist[tid];
    int lane = tid & 63, w = tid >> 6;
    int s = v;
    #pragma unroll
    for (int off = 1; off < 64; off <<= 1) {
        int t = __shfl_up(s, off, 64);
        if (lane >= off) s += t;
    }
    if (lane == 63) wsum[w] = s;
    __syncthreads();
    if (tid == 0) {
        int a = 0;
        #pragma unroll
        for (int i = 0; i < 8; i++) { int t = wsum[i]; wsum[i] = a; a += t; }
    }
    __syncthreads();
    int excl = s - v + wsum[w];
    int rbase = b << 9;
    if (rbase + tid <= N_NODES) rowptr[rbase + tid] = beg + excl;
    __syncthreads();
    hist[tid] = excl;            // reuse as cursor (beg-relative)
    __syncthreads();
    for (int i = beg + tid; i < end; i += 512) {
        int2 kv = est[i];
        int r9  = kv.x >> 18;
        int pos = beg + atomicAdd(&hist[r9], 1);           // LDS atomic
        es[pos] = make_int2(kv.x & 0x3FFFF, kv.y);
    }
}

// ---------- GCN ----------
// init: p0 = lrelu_l2norm(concat(upref, ipref)) in bf16 (no fp32 acc array)
__global__ void init_kernel(const float* __restrict__ upref,
                            const float* __restrict__ ipref,
                            ushort_t* __restrict__ p0) {
    int row  = blockIdx.x * 4 + (threadIdx.x >> 6);
    int lane = threadIdx.x & 63;
    if (row >= N_NODES) return;
    float x = (row < NUM_USERS) ? upref[(size_t)row * D + lane]
                                : ipref[(size_t)(row - NUM_USERS) * D + lane];
    x = (x >= 0.f) ? x : NEG_SLOPE * x;
    float norm = sqrtf(wave_sum64(x * x));
    float y = x / fmaxf(norm, EPS_NRM);
    p0[(size_t)row * D + lane] = f2bf(y);
}

// one wave per row; 8 edges in flight (sub = lane>>3), 8 features/lane (fl = lane&7)
__global__ void gather_kernel(const int* __restrict__ rowptr,
                              const int2* __restrict__ es,
                              const ushort_t* __restrict__ p,
                              ushort_t* __restrict__ pn) {
    int row  = blockIdx.x * 4 + (threadIdx.x >> 6);
    int lane = threadIdx.x & 63;
    if (row >= N_NODES) return;
    int sub = lane >> 3;
    int fl  = lane & 7;
    int beg = rowptr[row], end = rowptr[row + 1];

    float a[8];
    #pragma unroll
    for (int k = 0; k < 8; k++) a[k] = 0.f;

    for (int e = beg + sub; e < end; e += 8) {
        int2 cv = es[e];
        float v = __int_as_float(cv.y);
        const uint4 q = *(const uint4*)(p + ((unsigned)(cv.x << 6) | (fl << 3)));
        a[0] = fmaf(v, __uint_as_float(q.x << 16),         a[0]);
        a[1] = fmaf(v, __uint_as_float(q.x & 0xFFFF0000u), a[1]);
        a[2] = fmaf(v, __uint_as_float(q.y << 16),         a[2]);
        a[3] = fmaf(v, __uint_as_float(q.y & 0xFFFF0000u), a[3]);
        a[4] = fmaf(v, __uint_as_float(q.z << 16),         a[4]);
        a[5] = fmaf(v, __uint_as_float(q.z & 0xFFFF0000u), a[5]);
        a[6] = fmaf(v, __uint_as_float(q.w << 16),         a[6]);
        a[7] = fmaf(v, __uint_as_float(q.w & 0xFFFF0000u), a[7]);
    }
    #pragma unroll
    for (int k = 0; k < 8; k++) {
        a[k] += __shfl_xor(a[k], 8, 64);
        a[k] += __shfl_xor(a[k], 16, 64);
        a[k] += __shfl_xor(a[k], 32, 64);
    }

    float ss = 0.f;
    #pragma unroll
    for (int k = 0; k < 8; k++) {
        a[k] = (a[k] >= 0.f) ? a[k] : NEG_SLOPE * a[k];
        ss = fmaf(a[k], a[k], ss);
    }
    ss += __shfl_xor(ss, 1, 64);
    ss += __shfl_xor(ss, 2, 64);
    ss += __shfl_xor(ss, 4, 64);
    float inv = 1.f / fmaxf(sqrtf(ss), EPS_NRM);

    if (sub == 0) {
        uint4 o;
        o.x = (unsigned)f2bf(a[0] * inv) | ((unsigned)f2bf(a[1] * inv) << 16);
        o.y = (unsigned)f2bf(a[2] * inv) | ((unsigned)f2bf(a[3] * inv) << 16);
        o.z = (unsigned)f2bf(a[4] * inv) | ((unsigned)f2bf(a[5] * inv) << 16);
        o.w = (unsigned)f2bf(a[6] * inv) | ((unsigned)f2bf(a[7] * inv) << 16);
        *(uint4*)(pn + (size_t)row * D + fl * 8) = o;
    }
}

// one wave per batch element: sum 4 layer rows for the user once, then 3 item dots.
// merged = sum/4 on both sides -> product scaled by 1/16.
__global__ void score_kernel(const int* __restrict__ users,
                             const int* __restrict__ it0,
                             const int* __restrict__ it1,
                             const int* __restrict__ it2,
                             const ushort_t* __restrict__ p0,
                             const ushort_t* __restrict__ p1,
                             const ushort_t* __restrict__ p2,
                             const ushort_t* __restrict__ p3,
                             float* __restrict__ out) {
    int b    = blockIdx.x * 4 + (threadIdx.x >> 6);
    int lane = threadIdx.x & 63;
    if (b >= BATCH) return;
    int u = users[b];
    size_t uo = (size_t)u * D + lane;
    float uf = bf2f(p0[uo]) + bf2f(p1[uo]) + bf2f(p2[uo]) + bf2f(p3[uo]);

    int its[3];
    its[0] = it0[b]; its[1] = it1[b]; its[2] = it2[b];
    #pragma unroll
    for (int k = 0; k < 3; k++) {
        size_t io = (size_t)(NUM_USERS + its[k]) * D + lane;
        float itf = bf2f(p0[io]) + bf2f(p1[io]) + bf2f(p2[io]) + bf2f(p3[io]);
        float s = wave_sum64(uf * itf) * 0.0625f;
        if (lane == 0)
            out[k * BATCH + b] = 1.f / (1.f + expf(-s));
    }
}

extern "C" void kernel_launch(void* const* d_in, const int* in_sizes, int n_in,
                              void* d_out, int out_size, void* d_ws, size_t ws_size,
                              hipStream_t stream) {
    const int*   users  = (const int*)  d_in[0];
    const int*   adj    = (const int*)  d_in[1];
    const int*   weak   = (const int*)  d_in[2];
    const int*   strong = (const int*)  d_in[3];
    const int*   erows  = (const int*)  d_in[4];
    const int*   ecols  = (const int*)  d_in[5];
    const float* evals  = (const float*)d_in[6];
    const float* upref  = (const float*)d_in[7];
    const float* ipref  = (const float*)d_in[8];
    float* out = (float*)d_out;

    const size_t rowElems = (size_t)N_NODES * D;   // 9.6M

    char* base = (char*)d_ws;
    size_t off = 0;
    auto alloc = [&](size_t bytes) {
        char* p = base + off;
        off = (off + bytes + 255) & ~(size_t)255;
        return (void*)p;
    };
    ushort_t* p0     = (ushort_t*)alloc(rowElems * sizeof(ushort_t)); // 19.2 MB
    ushort_t* p1     = (ushort_t*)alloc(rowElems * sizeof(ushort_t)); // 19.2 MB
    ushort_t* p2     = (ushort_t*)alloc(rowElems * sizeof(ushort_t)); // 19.2 MB
    ushort_t* p3     = (ushort_t*)alloc(rowElems * sizeof(ushort_t)); // 19.2 MB
    int2*     es     = (int2*)    alloc((size_t)NNZ * sizeof(int2));  // 19.2 MB
    int*      ht     = (int*)     alloc((size_t)NH * sizeof(int));    // 0.6 MB
    int*      hoff   = (int*)     alloc((size_t)NH * sizeof(int));    // 0.6 MB
    int*      rowptr = (int*)     alloc((N_NODES + 1) * sizeof(int));
    int*      bsums  = (int*)     alloc(1024 * sizeof(int));
    // es_tmp aliases p2: p2 is first written by the layer-2 gather, which is
    // stream-ordered long after bucket_sort consumed est.
    int2*     est    = (int2*)p2;

    // ---- CSR build: bucket sort, zero global atomics ----
    bucket_hist   <<<NCHUNK, 256, 0, stream>>>(erows, ht);
    scan1_kernel  <<<NBH, 256, 0, stream>>>(ht, hoff, bsums, NH);
    scan2_kernel  <<<1, 1024, 0, stream>>>(bsums, NBH);
    scan3_kernel  <<<NBH, 256, 0, stream>>>(hoff, bsums, NH);
    bucket_scatter<<<NCHUNK, 256, 0, stream>>>(erows, ecols, evals, hoff, est);
    bucket_sort   <<<NBUCKET, 512, 0, stream>>>(est, hoff, es, rowptr);

    // ---- GCN layers (no acc array; layers kept separately in bf16) ----
    init_kernel<<<(N_NODES + 3) / 4, 256, 0, stream>>>(upref, ipref, p0);
    gather_kernel<<<(N_NODES + 3) / 4, 256, 0, stream>>>(rowptr, es, p0, p1);
    gather_kernel<<<(N_NODES + 3) / 4, 256, 0, stream>>>(rowptr, es, p1, p2);
    gather_kernel<<<(N_NODES + 3) / 4, 256, 0, stream>>>(rowptr, es, p2, p3);

    score_kernel<<<(BATCH + 3) / 4, 256, 0, stream>>>(users, adj, weak, strong,
                                                      p0, p1, p2, p3, out);
}

// Round 8
// 405.854 us; speedup vs baseline: 1.8261x; 1.0454x over previous
//
#include <hip/hip_runtime.h>
#include <math.h>

#define D 64
#define NUM_USERS 100000
#define NUM_ITEMS 50000
#define N_NODES 150000   // NUM_USERS + NUM_ITEMS
#define NNZ 2400000
#define BATCH 8192
#define NEG_SLOPE 0.1f
#define EPS_NRM 1e-12f

// bucket sort geometry: bucket = row >> 9 (512 rows/bucket)
#define NBUCKET 293                 // ceil(150000/512)
#define NCHUNK  512
#define CH      4688                // ceil(NNZ/NCHUNK)
#define NH      (NBUCKET * NCHUNK)  // 150016 (= 586*256 exactly)
#define NBH     (NH / 256)          // 586 scan blocks

typedef unsigned short ushort_t;

__device__ __forceinline__ float wave_sum64(float v) {
    #pragma unroll
    for (int off = 32; off > 0; off >>= 1)
        v += __shfl_xor(v, off, 64);
    return v;
}

__device__ __forceinline__ int wave_sum64_i(int v) {
    #pragma unroll
    for (int off = 32; off > 0; off >>= 1)
        v += __shfl_xor(v, off, 64);
    return v;
}

__device__ __forceinline__ float bf2f(ushort_t u) {
    return __uint_as_float(((unsigned)u) << 16);
}
__device__ __forceinline__ ushort_t f2bf(float f) {
    unsigned x = __float_as_uint(f);
    unsigned r = (x + 0x7FFFu + ((x >> 16) & 1u)) >> 16;   // RNE
    return (ushort_t)r;
}

// ---------- CSR build: 2-level bucket sort, LDS atomics only ----------

__global__ void bucket_hist(const int* __restrict__ rows, int* __restrict__ ht) {
    __shared__ int hist[NBUCKET];
    int c = blockIdx.x, tid = threadIdx.x;
    for (int b = tid; b < NBUCKET; b += 256) hist[b] = 0;
    __syncthreads();
    int base = c * CH;
    for (int i = tid; i < CH; i += 256) {
        int e = base + i;
        if (e < NNZ) atomicAdd(&hist[rows[e] >> 9], 1);
    }
    __syncthreads();
    for (int b = tid; b < NBUCKET; b += 256) ht[b * NCHUNK + c] = hist[b];
}

__global__ void scan1_kernel(const int* __restrict__ in, int* __restrict__ out,
                             int* __restrict__ bsums, int n) {
    int tid = threadIdx.x, gid = blockIdx.x * 256 + tid;
    int v = (gid < n) ? in[gid] : 0;
    int lane = tid & 63, w = tid >> 6;
    int s = v;
    #pragma unroll
    for (int off = 1; off < 64; off <<= 1) {
        int t = __shfl_up(s, off, 64);
        if (lane >= off) s += t;
    }
    __shared__ int wsum[4];
    if (lane == 63) wsum[w] = s;
    __syncthreads();
    if (tid == 0) {
        int a = 0;
        #pragma unroll
        for (int i = 0; i < 4; i++) { int t = wsum[i]; wsum[i] = a; a += t; }
    }
    __syncthreads();
    int incl = s + wsum[w];
    if (gid < n) out[gid] = incl - v;           // exclusive
    if (tid == 255) bsums[blockIdx.x] = incl;   // block total (unscanned)
}

// fused: each block reduces bsums[0..b) itself, then adds to its 256 elems
__global__ void scan3_kernel(int* __restrict__ out, const int* __restrict__ bsums, int n) {
    __shared__ int wtot[4];
    __shared__ int total;
    int b = blockIdx.x, tid = threadIdx.x;
    int lane = tid & 63, w = tid >> 6;
    int partial = 0;
    for (int i = tid; i < b; i += 256) partial += bsums[i];
    partial = wave_sum64_i(partial);
    if (lane == 0) wtot[w] = partial;
    __syncthreads();
    if (tid == 0) total = wtot[0] + wtot[1] + wtot[2] + wtot[3];
    __syncthreads();
    int gid = b * 256 + tid;
    if (gid < n) out[gid] += total;
}

__global__ void bucket_scatter(const int* __restrict__ rows, const int* __restrict__ cols,
                               const float* __restrict__ vals, const int* __restrict__ hoff,
                               int2* __restrict__ est) {
    __shared__ int cur[NBUCKET];
    int c = blockIdx.x, tid = threadIdx.x;
    for (int b = tid; b < NBUCKET; b += 256) cur[b] = hoff[b * NCHUNK + c];
    __syncthreads();
    int base = c * CH;
    for (int i = tid; i < CH; i += 256) {
        int e = base + i;
        if (e < NNZ) {
            int r = rows[e];
            int pos = atomicAdd(&cur[r >> 9], 1);          // LDS atomic
            est[pos] = make_int2(cols[e] | ((r & 511) << 18), __float_as_int(vals[e]));
        }
    }
}

__global__ void __launch_bounds__(512) bucket_sort(const int2* __restrict__ est,
                                                   const int* __restrict__ hoff,
                                                   int2* __restrict__ es,
                                                   int* __restrict__ rowptr) {
    __shared__ int hist[512];
    __shared__ int wsum[8];
    int b = blockIdx.x, tid = threadIdx.x;
    int beg = hoff[b * NCHUNK];
    int end = (b == NBUCKET - 1) ? NNZ : hoff[(b + 1) * NCHUNK];
    hist[tid] = 0;
    __syncthreads();
    for (int i = beg + tid; i < end; i += 512)
        atomicAdd(&hist[est[i].x >> 18], 1);
    __syncthreads();
    int v = hist[tid];
    int lane = tid & 63, w = tid >> 6;
    int s = v;
    #pragma unroll
    for (int off = 1; off < 64; off <<= 1) {
        int t = __shfl_up(s, off, 64);
        if (lane >= off) s += t;
    }
    if (lane == 63) wsum[w] = s;
    __syncthreads();
    if (tid == 0) {
        int a = 0;
        #pragma unroll
        for (int i = 0; i < 8; i++) { int t = wsum[i]; wsum[i] = a; a += t; }
    }
    __syncthreads();
    int excl = s - v + wsum[w];
    int rbase = b << 9;
    if (rbase + tid <= N_NODES) rowptr[rbase + tid] = beg + excl;
    __syncthreads();
    hist[tid] = excl;            // reuse as cursor (beg-relative)
    __syncthreads();
    for (int i = beg + tid; i < end; i += 512) {
        int2 kv = est[i];
        int r9  = kv.x >> 18;
        int pos = beg + atomicAdd(&hist[r9], 1);           // LDS atomic
        es[pos] = make_int2(kv.x & 0x3FFFF, kv.y);
    }
}

// ---------- GCN ----------
__global__ void init_kernel(const float* __restrict__ upref,
                            const float* __restrict__ ipref,
                            ushort_t* __restrict__ p0) {
    int row  = blockIdx.x * 4 + (threadIdx.x >> 6);
    int lane = threadIdx.x & 63;
    if (row >= N_NODES) return;
    float x = (row < NUM_USERS) ? upref[(size_t)row * D + lane]
                                : ipref[(size_t)(row - NUM_USERS) * D + lane];
    x = (x >= 0.f) ? x : NEG_SLOPE * x;
    float norm = sqrtf(wave_sum64(x * x));
    float y = x / fmaxf(norm, EPS_NRM);
    p0[(size_t)row * D + lane] = f2bf(y);
}

// one wave per row; 8 edge-slots (sub = lane>>3), 8 features/lane (fl = lane&7);
// edge loop manually unrolled 2x -> up to 16 independent p-gathers in flight.
__global__ void gather_kernel(const int* __restrict__ rowptr,
                              const int2* __restrict__ es,
                              const ushort_t* __restrict__ p,
                              ushort_t* __restrict__ pn) {
    int row  = blockIdx.x * 4 + (threadIdx.x >> 6);
    int lane = threadIdx.x & 63;
    if (row >= N_NODES) return;
    int sub = lane >> 3;
    int fl  = lane & 7;
    int beg = rowptr[row], end = rowptr[row + 1];

    float a[8];
    #pragma unroll
    for (int k = 0; k < 8; k++) a[k] = 0.f;

    int e = beg + sub;
    // 2x unrolled main loop: both es loads, then both p gathers, then 16 fmas
    while (e + 8 < end) {
        int2 cv0 = es[e];
        int2 cv1 = es[e + 8];
        float v0 = __int_as_float(cv0.y);
        float v1 = __int_as_float(cv1.y);
        const uint4 q0 = *(const uint4*)(p + ((unsigned)(cv0.x << 6) | (fl << 3)));
        const uint4 q1 = *(const uint4*)(p + ((unsigned)(cv1.x << 6) | (fl << 3)));
        a[0] = fmaf(v0, __uint_as_float(q0.x << 16),         a[0]);
        a[1] = fmaf(v0, __uint_as_float(q0.x & 0xFFFF0000u), a[1]);
        a[2] = fmaf(v0, __uint_as_float(q0.y << 16),         a[2]);
        a[3] = fmaf(v0, __uint_as_float(q0.y & 0xFFFF0000u), a[3]);
        a[4] = fmaf(v0, __uint_as_float(q0.z << 16),         a[4]);
        a[5] = fmaf(v0, __uint_as_float(q0.z & 0xFFFF0000u), a[5]);
        a[6] = fmaf(v0, __uint_as_float(q0.w << 16),         a[6]);
        a[7] = fmaf(v0, __uint_as_float(q0.w & 0xFFFF0000u), a[7]);
        a[0] = fmaf(v1, __uint_as_float(q1.x << 16),         a[0]);
        a[1] = fmaf(v1, __uint_as_float(q1.x & 0xFFFF0000u), a[1]);
        a[2] = fmaf(v1, __uint_as_float(q1.y << 16),         a[2]);
        a[3] = fmaf(v1, __uint_as_float(q1.y & 0xFFFF0000u), a[3]);
        a[4] = fmaf(v1, __uint_as_float(q1.z << 16),         a[4]);
        a[5] = fmaf(v1, __uint_as_float(q1.z & 0xFFFF0000u), a[5]);
        a[6] = fmaf(v1, __uint_as_float(q1.w << 16),         a[6]);
        a[7] = fmaf(v1, __uint_as_float(q1.w & 0xFFFF0000u), a[7]);
        e += 16;
    }
    if (e < end) {
        int2 cv = es[e];
        float v = __int_as_float(cv.y);
        const uint4 q = *(const uint4*)(p + ((unsigned)(cv.x << 6) | (fl << 3)));
        a[0] = fmaf(v, __uint_as_float(q.x << 16),         a[0]);
        a[1] = fmaf(v, __uint_as_float(q.x & 0xFFFF0000u), a[1]);
        a[2] = fmaf(v, __uint_as_float(q.y << 16),         a[2]);
        a[3] = fmaf(v, __uint_as_float(q.y & 0xFFFF0000u), a[3]);
        a[4] = fmaf(v, __uint_as_float(q.z << 16),         a[4]);
        a[5] = fmaf(v, __uint_as_float(q.z & 0xFFFF0000u), a[5]);
        a[6] = fmaf(v, __uint_as_float(q.w << 16),         a[6]);
        a[7] = fmaf(v, __uint_as_float(q.w & 0xFFFF0000u), a[7]);
    }

    #pragma unroll
    for (int k = 0; k < 8; k++) {
        a[k] += __shfl_xor(a[k], 8, 64);
        a[k] += __shfl_xor(a[k], 16, 64);
        a[k] += __shfl_xor(a[k], 32, 64);
    }

    float ss = 0.f;
    #pragma unroll
    for (int k = 0; k < 8; k++) {
        a[k] = (a[k] >= 0.f) ? a[k] : NEG_SLOPE * a[k];
        ss = fmaf(a[k], a[k], ss);
    }
    ss += __shfl_xor(ss, 1, 64);
    ss += __shfl_xor(ss, 2, 64);
    ss += __shfl_xor(ss, 4, 64);
    float inv = 1.f / fmaxf(sqrtf(ss), EPS_NRM);

    if (sub == 0) {
        uint4 o;
        o.x = (unsigned)f2bf(a[0] * inv) | ((unsigned)f2bf(a[1] * inv) << 16);
        o.y = (unsigned)f2bf(a[2] * inv) | ((unsigned)f2bf(a[3] * inv) << 16);
        o.z = (unsigned)f2bf(a[4] * inv) | ((unsigned)f2bf(a[5] * inv) << 16);
        o.w = (unsigned)f2bf(a[6] * inv) | ((unsigned)f2bf(a[7] * inv) << 16);
        *(uint4*)(pn + (size_t)row * D + fl * 8) = o;
    }
}

// one wave per batch element: sum 4 layer rows for the user once, then 3 item dots.
__global__ void score_kernel(const int* __restrict__ users,
                             const int* __restrict__ it0,
                             const int* __restrict__ it1,
                             const int* __restrict__ it2,
                             const ushort_t* __restrict__ p0,
                             const ushort_t* __restrict__ p1,
                             const ushort_t* __restrict__ p2,
                             const ushort_t* __restrict__ p3,
                             float* __restrict__ out) {
    int b    = blockIdx.x * 4 + (threadIdx.x >> 6);
    int lane = threadIdx.x & 63;
    if (b >= BATCH) return;
    int u = users[b];
    size_t uo = (size_t)u * D + lane;
    float uf = bf2f(p0[uo]) + bf2f(p1[uo]) + bf2f(p2[uo]) + bf2f(p3[uo]);

    int its[3];
    its[0] = it0[b]; its[1] = it1[b]; its[2] = it2[b];
    #pragma unroll
    for (int k = 0; k < 3; k++) {
        size_t io = (size_t)(NUM_USERS + its[k]) * D + lane;
        float itf = bf2f(p0[io]) + bf2f(p1[io]) + bf2f(p2[io]) + bf2f(p3[io]);
        float s = wave_sum64(uf * itf) * 0.0625f;
        if (lane == 0)
            out[k * BATCH + b] = 1.f / (1.f + expf(-s));
    }
}

extern "C" void kernel_launch(void* const* d_in, const int* in_sizes, int n_in,
                              void* d_out, int out_size, void* d_ws, size_t ws_size,
                              hipStream_t stream) {
    const int*   users  = (const int*)  d_in[0];
    const int*   adj    = (const int*)  d_in[1];
    const int*   weak   = (const int*)  d_in[2];
    const int*   strong = (const int*)  d_in[3];
    const int*   erows  = (const int*)  d_in[4];
    const int*   ecols  = (const int*)  d_in[5];
    const float* evals  = (const float*)d_in[6];
    const float* upref  = (const float*)d_in[7];
    const float* ipref  = (const float*)d_in[8];
    float* out = (float*)d_out;

    const size_t rowElems = (size_t)N_NODES * D;   // 9.6M

    char* base = (char*)d_ws;
    size_t off = 0;
    auto alloc = [&](size_t bytes) {
        char* p = base + off;
        off = (off + bytes + 255) & ~(size_t)255;
        return (void*)p;
    };
    ushort_t* p0     = (ushort_t*)alloc(rowElems * sizeof(ushort_t)); // 19.2 MB
    ushort_t* p1     = (ushort_t*)alloc(rowElems * sizeof(ushort_t)); // 19.2 MB
    ushort_t* p2     = (ushort_t*)alloc(rowElems * sizeof(ushort_t)); // 19.2 MB
    ushort_t* p3     = (ushort_t*)alloc(rowElems * sizeof(ushort_t)); // 19.2 MB
    int2*     es     = (int2*)    alloc((size_t)NNZ * sizeof(int2));  // 19.2 MB
    int*      ht     = (int*)     alloc((size_t)NH * sizeof(int));    // 0.6 MB
    int*      hoff   = (int*)     alloc((size_t)NH * sizeof(int));    // 0.6 MB
    int*      rowptr = (int*)     alloc((N_NODES + 1) * sizeof(int));
    int*      bsums  = (int*)     alloc(1024 * sizeof(int));
    // es_tmp aliases p2: p2 is first written by the layer-2 gather, which is
    // stream-ordered long after bucket_sort consumed est.
    int2*     est    = (int2*)p2;

    // ---- CSR build: bucket sort, zero global atomics ----
    bucket_hist   <<<NCHUNK, 256, 0, stream>>>(erows, ht);
    scan1_kernel  <<<NBH, 256, 0, stream>>>(ht, hoff, bsums, NH);
    scan3_kernel  <<<NBH, 256, 0, stream>>>(hoff, bsums, NH);
    bucket_scatter<<<NCHUNK, 256, 0, stream>>>(erows, ecols, evals, hoff, est);
    bucket_sort   <<<NBUCKET, 512, 0, stream>>>(est, hoff, es, rowptr);

    // ---- GCN layers (no acc array; layers kept separately in bf16) ----
    init_kernel<<<(N_NODES + 3) / 4, 256, 0, stream>>>(upref, ipref, p0);
    gather_kernel<<<(N_NODES + 3) / 4, 256, 0, stream>>>(rowptr, es, p0, p1);
    gather_kernel<<<(N_NODES + 3) / 4, 256, 0, stream>>>(rowptr, es, p1, p2);
    gather_kernel<<<(N_NODES + 3) / 4, 256, 0, stream>>>(rowptr, es, p2, p3);

    score_kernel<<<(BATCH + 3) / 4, 256, 0, stream>>>(users, adj, weak, strong,
                                                      p0, p1, p2, p3, out);
}